// Round 13
// baseline (183.935 us; speedup 1.0000x reference)
//
#include <hip/hip_runtime.h>
#include <hip/hip_bf16.h>
#include <cstdint>

#define DEV static __device__ __forceinline__

typedef __attribute__((ext_vector_type(8))) short bf16x8;
typedef __attribute__((ext_vector_type(4))) float f32x4;
typedef __attribute__((ext_vector_type(4))) float float4v;
typedef __attribute__((ext_vector_type(8))) unsigned short us8;
typedef __attribute__((ext_vector_type(4))) unsigned short us4;

constexpr int SEQ = 2048;
constexpr int DM = 512;
constexpr float INV_SCALE = 0.044194173824159216f;  // 1/sqrt(512)
constexpr float LOG2E = 1.4426950408889634f;
constexpr float SEXP = INV_SCALE * LOG2E;           // score -> exp2 arg

DEV unsigned short f2bf(float f) {  // RNE f32 -> bf16 bits
  unsigned int u = __float_as_uint(f);
  u = u + 0x7FFFu + ((u >> 16) & 1u);
  return (unsigned short)(u >> 16);
}
DEV float bf2f(unsigned short h) { return __uint_as_float(((unsigned int)h) << 16); }

DEV void gload_lds16(const void* g, void* l) {
  __builtin_amdgcn_global_load_lds(
      (const __attribute__((address_space(1))) void*)g,
      (__attribute__((address_space(3))) void*)l, 16, 0, 0);
}

// ---------------- cast kernels ----------------
__global__ void convert_x_kernel(const float* __restrict__ x, unsigned short* __restrict__ xb) {
  int64_t i = ((int64_t)blockIdx.x * 256 + threadIdx.x) * 8;
  float4v a = *(const float4v*)(x + i);
  float4v b = *(const float4v*)(x + i + 4);
  us8 o;
  o[0] = f2bf(a[0]); o[1] = f2bf(a[1]); o[2] = f2bf(a[2]); o[3] = f2bf(a[3]);
  o[4] = f2bf(b[0]); o[5] = f2bf(b[1]); o[6] = f2bf(b[2]); o[7] = f2bf(b[3]);
  *(us8*)(xb + i) = o;
}

__global__ void convert_w_kernel(const float* __restrict__ wq, const float* __restrict__ wk,
                                 const float* __restrict__ wv, unsigned short* __restrict__ wb) {
  int w = blockIdx.x >> 8;
  int blk = blockIdx.x & 255;
  const float* src = (w == 0) ? wq : ((w == 1) ? wk : wv);
  int i = (blk * 256 + (int)threadIdx.x) * 4;
  float4v a = *(const float4v*)(src + i);
  us4 o;
  o[0] = f2bf(a[0]); o[1] = f2bf(a[1]); o[2] = f2bf(a[2]); o[3] = f2bf(a[3]);
  *(us4*)(wb + (w << 18) + i) = o;
}

// ---------------- fused QKV GEMM ----------------
// grid (128 mtiles, 4 ntiles, 3 which). Skips Q/K tiles fully >= L (never read).
__global__ __launch_bounds__(256) void qkv_gemm_kernel(
    const unsigned short* __restrict__ xb, const unsigned short* __restrict__ wb,
    const float* __restrict__ bq, const float* __restrict__ bk, const float* __restrict__ bv,
    const int* __restrict__ ev,
    unsigned short* __restrict__ Qb, unsigned short* __restrict__ Kb,
    unsigned short* __restrict__ VTb)
{
  const int which = blockIdx.z;
  const int m0 = blockIdx.x << 7;
  const int n0 = blockIdx.y << 7;
  if (which < 2) {   // Q/K rows in fully-masked tiles are never read downstream
    const int L = ev[m0 >> 11];
    if ((m0 & 2047) >= L) return;
  }
  const unsigned short* W = wb + ((int64_t)which << 18);
  const int tid = threadIdx.x;
  const int lane = tid & 63, wid = tid >> 6;
  const int lo = lane & 15, hi = lane >> 4;
  const int wrow = wid >> 1, wcol = wid & 1;

  __shared__ alignas(16) unsigned short lA[128 * 64];
  __shared__ alignas(16) unsigned short lB[128 * 64];

  f32x4 acc[4][4];
  #pragma unroll
  for (int i = 0; i < 4; ++i)
    #pragma unroll
    for (int j = 0; j < 4; ++j) acc[i][j] = (f32x4){0.f, 0.f, 0.f, 0.f};

  for (int k0 = 0; k0 < 512; k0 += 64) {
    if (k0) __syncthreads();
    #pragma unroll
    for (int i = 0; i < 4; ++i) {
      const int m = (i << 8) + tid;
      const int mw = (i << 8) + (wid << 6);
      const int row = m >> 3, c = m & 7;
      const int ca = c ^ (row & 7);
      gload_lds16(xb + ((int64_t)(m0 + row) << 9) + k0 + (ca << 3), lA + (mw << 3));
      gload_lds16(W  + ((int64_t)(n0 + row) << 9) + k0 + (ca << 3), lB + (mw << 3));
    }
    __syncthreads();

    #pragma unroll
    for (int ks = 0; ks < 2; ++ks) {
      bf16x8 af[4], bfr[4];
      #pragma unroll
      for (int mf = 0; mf < 4; ++mf) {
        const int row = (wrow << 6) + (mf << 4) + lo;
        const int cc = ((ks << 2) + hi) ^ (row & 7);
        af[mf] = *(const bf16x8*)(lA + (row << 6) + (cc << 3));
      }
      #pragma unroll
      for (int nf = 0; nf < 4; ++nf) {
        const int row = (wcol << 6) + (nf << 4) + lo;
        const int cc = ((ks << 2) + hi) ^ (row & 7);
        bfr[nf] = *(const bf16x8*)(lB + (row << 6) + (cc << 3));
      }
      #pragma unroll
      for (int mf = 0; mf < 4; ++mf)
        #pragma unroll
        for (int nf = 0; nf < 4; ++nf)
          acc[mf][nf] = __builtin_amdgcn_mfma_f32_16x16x32_bf16(af[mf], bfr[nf], acc[mf][nf], 0, 0, 0);
    }
  }

  const float* bias = (which == 0) ? bq : ((which == 1) ? bk : bv);
  if (which < 2) {
    unsigned short* outp = (which == 0) ? Qb : Kb;
    #pragma unroll
    for (int nf = 0; nf < 4; ++nf) {
      const int e = n0 + (wcol << 6) + (nf << 4) + lo;
      const float bb = bias[e];
      #pragma unroll
      for (int mf = 0; mf < 4; ++mf) {
        const int rowg = m0 + (wrow << 6) + (mf << 4) + (hi << 2);
        #pragma unroll
        for (int r = 0; r < 4; ++r)
          outp[((int64_t)(rowg + r) << 9) + e] = f2bf(acc[mf][nf][r] + bb);
      }
    }
  } else {
    #pragma unroll
    for (int nf = 0; nf < 4; ++nf) {
      const int e = n0 + (wcol << 6) + (nf << 4) + lo;
      const float bb = bias[e];
      #pragma unroll
      for (int mf = 0; mf < 4; ++mf) {
        const int rowg = m0 + (wrow << 6) + (mf << 4) + (hi << 2);
        const int bidx = rowg >> 11;
        const int s = rowg & 2047;
        us4 pk;
        pk[0] = f2bf(acc[mf][nf][0] + bb);
        pk[1] = f2bf(acc[mf][nf][1] + bb);
        pk[2] = f2bf(acc[mf][nf][2] + bb);
        pk[3] = f2bf(acc[mf][nf][3] + bb);
        *(us4*)(VTb + (((int64_t)(bidx << 9) + e) << 11) + s) = pk;
      }
    }
  }
}

// ---------------- per-batch mean of V rows ----------------
__global__ void vmean_kernel(const unsigned short* __restrict__ VTb, float* __restrict__ vmean) {
  const int row = blockIdx.x;  // b*512 + d
  const unsigned short* src = VTb + (int64_t)row * SEQ;
  const int tid = threadIdx.x;
  us8 v = *(const us8*)(src + tid * 8);
  float s = 0.f;
  #pragma unroll
  for (int j = 0; j < 8; ++j) s += bf2f(v[j]);
  #pragma unroll
  for (int off = 1; off < 64; off <<= 1) s += __shfl_xor(s, off);
  __shared__ float ps[4];
  const int lane = tid & 63, wid = tid >> 6;
  if (lane == 0) ps[wid] = s;
  __syncthreads();
  if (tid == 0) vmean[row] = (ps[0] + ps[1] + ps[2] + ps[3]) * (1.f / 2048.f);
}

// ---------------- pass 1: P = exp(Q K^T * inv_scale), masked, bf16 ----------------
// grid (16 qtiles, 16 ktiles, nb batches), 256 thr. P[z][2048][2048].
__global__ __launch_bounds__(256) void score_gemm_kernel(
    const unsigned short* __restrict__ Qb, const unsigned short* __restrict__ Kb,
    const int* __restrict__ ev, unsigned short* __restrict__ P, int b0)
{
  const int z = blockIdx.z;
  const int b = b0 + z;
  const int L = ev[b];
  const int q0 = blockIdx.x << 7;
  const int k0g = blockIdx.y << 7;
  if (q0 >= L || k0g >= L) return;   // tile never read by pv pass

  const unsigned short* Qrows = Qb + ((int64_t)b << 20);
  const unsigned short* Krows = Kb + ((int64_t)b << 20);
  const int tid = threadIdx.x;
  const int lane = tid & 63, wid = tid >> 6;
  const int lo = lane & 15, hi = lane >> 4;
  const int wrow = wid >> 1, wcol = wid & 1;

  __shared__ alignas(16) unsigned short lA[128 * 64];
  __shared__ alignas(16) unsigned short lB[128 * 64];

  f32x4 acc[4][4];
  #pragma unroll
  for (int i = 0; i < 4; ++i)
    #pragma unroll
    for (int j = 0; j < 4; ++j) acc[i][j] = (f32x4){0.f, 0.f, 0.f, 0.f};

  for (int k0 = 0; k0 < 512; k0 += 64) {   // contraction over d
    if (k0) __syncthreads();
    #pragma unroll
    for (int i = 0; i < 4; ++i) {
      const int m = (i << 8) + tid;
      const int mw = (i << 8) + (wid << 6);
      const int row = m >> 3, c = m & 7;
      const int ca = c ^ (row & 7);
      gload_lds16(Qrows + ((int64_t)(q0 + row) << 9) + k0 + (ca << 3), lA + (mw << 3));
      gload_lds16(Krows + ((int64_t)(k0g + row) << 9) + k0 + (ca << 3), lB + (mw << 3));
    }
    __syncthreads();

    #pragma unroll
    for (int ks = 0; ks < 2; ++ks) {
      bf16x8 af[4], bfr[4];
      #pragma unroll
      for (int mf = 0; mf < 4; ++mf) {
        const int row = (wrow << 6) + (mf << 4) + lo;
        const int cc = ((ks << 2) + hi) ^ (row & 7);
        af[mf] = *(const bf16x8*)(lA + (row << 6) + (cc << 3));
      }
      #pragma unroll
      for (int nf = 0; nf < 4; ++nf) {
        const int row = (wcol << 6) + (nf << 4) + lo;
        const int cc = ((ks << 2) + hi) ^ (row & 7);
        bfr[nf] = *(const bf16x8*)(lB + (row << 6) + (cc << 3));
      }
      #pragma unroll
      for (int mf = 0; mf < 4; ++mf)
        #pragma unroll
        for (int nf = 0; nf < 4; ++nf)
          acc[mf][nf] = __builtin_amdgcn_mfma_f32_16x16x32_bf16(af[mf], bfr[nf], acc[mf][nf], 0, 0, 0);
    }
  }

  // epilogue: p = exp2(s*SEXP) with mask, bf16 store
  unsigned short* Pz = P + ((int64_t)z << 22);
  #pragma unroll
  for (int nf = 0; nf < 4; ++nf) {
    const int kcol = k0g + (wcol << 6) + (nf << 4) + lo;
    const bool kok = kcol < L;
    #pragma unroll
    for (int mf = 0; mf < 4; ++mf) {
      const int rowg = q0 + (wrow << 6) + (mf << 4) + (hi << 2);
      #pragma unroll
      for (int r = 0; r < 4; ++r) {
        const float p = (kok && (rowg + r < L)) ? exp2f(acc[mf][nf][r] * SEXP) : 0.f;
        Pz[((int64_t)(rowg + r) << 11) + kcol] = f2bf(p);
      }
    }
  }
}

// ---------------- pass 2: O = P V / rowsum(P), rows>=L -> vmean ----------------
// grid (32 qtiles of 64, 4 dtiles, nb batches), 256 thr.
// v3: NO LDS staging — P (L3-resident) and V (L2-resident) fragments are read
// directly from global at MFMA fragment addresses. Zero barriers in the K-loop;
// occupancy is VGPR-bound, TLP hides cache latency (Common-mistake #7 fix).
__global__ __launch_bounds__(256) void pv_gemm_kernel(
    const unsigned short* __restrict__ P, const unsigned short* __restrict__ VTb,
    const float* __restrict__ vmean, const int* __restrict__ ev,
    float* __restrict__ out, int b0)
{
  const int z = blockIdx.z;
  const int b = b0 + z;
  const int L = ev[b];
  const int q0 = blockIdx.x << 6;   // 64 q-rows
  const int d0 = blockIdx.y << 7;   // 128 d-cols
  const int tid = threadIdx.x;

  float* outb = out + ((int64_t)b << 20);
  const float* vm = vmean + (b << 9);

  if (q0 >= L) {  // fully masked q-tile: uniform average of all V rows
    #pragma unroll
    for (int j = 0; j < 8; ++j) {
      const int idx = tid + (j << 8);          // 0..2047 float4s = 64x128 f32
      const int r = idx >> 5, c = (idx & 31) << 2;
      *(float4v*)(outb + ((int64_t)(q0 + r) << 9) + d0 + c) = *(const float4v*)(vm + d0 + c);
    }
    return;
  }

  const int lane = tid & 63, wid = tid >> 6;
  const int lo = lane & 15, hi = lane >> 4;
  const int wrow = wid >> 1, wcol = wid & 1;   // wave tile: 32q x 64d

  __shared__ float lpart[64][4];

  const unsigned short* Pz = P + ((int64_t)z << 22);
  const unsigned short* Vrows = VTb + ((int64_t)(b << 9) << 11);

  // per-lane fragment base pointers
  const unsigned short* pa0 = Pz + ((int64_t)(q0 + (wrow << 5) + lo) << 11) + (hi << 3);
  const unsigned short* pb0 = Vrows + ((int64_t)(d0 + (wcol << 6) + lo) << 11) + (hi << 3);

  f32x4 acc[2][4];
  #pragma unroll
  for (int i = 0; i < 2; ++i)
    #pragma unroll
    for (int j = 0; j < 4; ++j) acc[i][j] = (f32x4){0.f, 0.f, 0.f, 0.f};
  float ls[2] = {0.f, 0.f};

  const int nk = (L + 63) >> 6;
  for (int kk = 0; kk < nk; ++kk) {
    const int kb = kk << 6;
    #pragma unroll
    for (int ks = 0; ks < 2; ++ks) {
      const int ko = kb + (ks << 5);           // + hi*8 folded into base
      bf16x8 af[2], bfr[4];
      #pragma unroll
      for (int mf = 0; mf < 2; ++mf)           // A rows: wrow*32 + mf*16 + lo
        af[mf] = *(const bf16x8*)(pa0 + ((int64_t)(mf << 4) << 11) + ko);
      #pragma unroll
      for (int nf = 0; nf < 4; ++nf)           // B rows: wcol*64 + nf*16 + lo
        bfr[nf] = *(const bf16x8*)(pb0 + ((int64_t)(nf << 4) << 11) + ko);
      if (wcol == 0) {  // row-sums of P from A fragments (l accumulation)
        #pragma unroll
        for (int mf = 0; mf < 2; ++mf) {
          float t = 0.f;
          #pragma unroll
          for (int j = 0; j < 8; ++j) t += bf2f((unsigned short)af[mf][j]);
          ls[mf] += t;
        }
      }
      #pragma unroll
      for (int mf = 0; mf < 2; ++mf)
        #pragma unroll
        for (int nf = 0; nf < 4; ++nf)
          acc[mf][nf] = __builtin_amdgcn_mfma_f32_16x16x32_bf16(af[mf], bfr[nf], acc[mf][nf], 0, 0, 0);
    }
  }

  if (wcol == 0) {
    #pragma unroll
    for (int mf = 0; mf < 2; ++mf)
      lpart[(wrow << 5) + (mf << 4) + lo][hi] = ls[mf];
  }
  __syncthreads();

  // epilogue: normalize, mask tail rows to vmean
  #pragma unroll
  for (int mf = 0; mf < 2; ++mf) {
    const int rowb = (wrow << 5) + (mf << 4) + (hi << 2);
    float rl[4];
    #pragma unroll
    for (int r = 0; r < 4; ++r) {
      const float l = lpart[rowb + r][0] + lpart[rowb + r][1] +
                      lpart[rowb + r][2] + lpart[rowb + r][3];
      rl[r] = 1.0f / l;
    }
    #pragma unroll
    for (int nf = 0; nf < 4; ++nf) {
      const int col = d0 + (wcol << 6) + (nf << 4) + lo;
      const float vmc = vm[col];
      #pragma unroll
      for (int r = 0; r < 4; ++r) {
        const int rowg = q0 + rowb + r;
        const float val = (rowg < L) ? (acc[mf][nf][r] * rl[r]) : vmc;
        outb[((int64_t)rowg << 9) + col] = val;
      }
    }
  }
}

// ---------------- launcher ----------------
extern "C" void kernel_launch(void* const* d_in, const int* in_sizes, int n_in,
                              void* d_out, int out_size, void* d_ws, size_t ws_size,
                              hipStream_t stream) {
  const float* x  = (const float*)d_in[0];
  const int* ev   = (const int*)d_in[1];
  const float* Wq = (const float*)d_in[2];
  const float* bq = (const float*)d_in[3];
  const float* Wk = (const float*)d_in[4];
  const float* bk = (const float*)d_in[5];
  const float* Wv = (const float*)d_in[6];
  const float* bv = (const float*)d_in[7];
  float* out = (float*)d_out;

  unsigned short* xb  = (unsigned short*)d_ws;          // [16384][512]; dead after qkv
  unsigned short* wb  = xb + (int64_t)16384 * 512;      // [3][512][512]
  unsigned short* Qb  = wb + 3 * 512 * 512;             // [16384][512]
  unsigned short* Kb  = Qb + (int64_t)16384 * 512;      // [16384][512]
  unsigned short* VTb = Kb + (int64_t)16384 * 512;      // [8][512][2048]
  float* vmean = (float*)(VTb + (int64_t)16384 * 512);  // [8][512]
  unsigned short* Ptail = (unsigned short*)(vmean + 8 * 512);

  // pick largest per-pass batch count that fits the workspace
  const size_t base_bytes = (size_t)((char*)Ptail - (char*)d_ws);  // 85,475,328
  const size_t pbytes = (size_t)SEQ * SEQ * 2;                     // 8 MB per batch
  int nb;
  unsigned short* P;
  if (ws_size >= base_bytes + 8 * pbytes)      { nb = 8; P = Ptail; }
  else if (ws_size >= base_bytes + 4 * pbytes) { nb = 4; P = Ptail; }
  else                                         { nb = 2; P = xb; }  // alias fallback

  convert_x_kernel<<<4096, 256, 0, stream>>>(x, xb);
  convert_w_kernel<<<768, 256, 0, stream>>>(Wq, Wk, Wv, wb);
  qkv_gemm_kernel<<<dim3(128, 4, 3), 256, 0, stream>>>(xb, wb, bq, bk, bv, ev, Qb, Kb, VTb);
  vmean_kernel<<<4096, 256, 0, stream>>>(VTb, vmean);

  for (int c = 0; c < 8 / nb; ++c) {
    score_gemm_kernel<<<dim3(16, 16, nb), 256, 0, stream>>>(Qb, Kb, ev, P, c * nb);
    pv_gemm_kernel<<<dim3(32, 4, nb), 256, 0, stream>>>(P, VTb, vmean, ev, out, c * nb);
  }
}

// Round 14
// 112.151 us; speedup vs baseline: 1.6401x; 1.6401x over previous
//
#include <hip/hip_runtime.h>
#include <hip/hip_bf16.h>
#include <cstdint>

#define DEV static __device__ __forceinline__

typedef __attribute__((ext_vector_type(8))) short bf16x8;
typedef __attribute__((ext_vector_type(4))) float f32x4;
typedef __attribute__((ext_vector_type(4))) float float4v;
typedef __attribute__((ext_vector_type(8))) unsigned short us8;
typedef __attribute__((ext_vector_type(4))) unsigned short us4;

constexpr int SEQ = 2048;
constexpr int DM = 512;
constexpr float INV_SCALE = 0.044194173824159216f;  // 1/sqrt(512)
constexpr float LOG2E = 1.4426950408889634f;
constexpr float SEXP = INV_SCALE * LOG2E;           // score -> exp2 arg

DEV unsigned short f2bf(float f) {  // RNE f32 -> bf16 bits
  unsigned int u = __float_as_uint(f);
  u = u + 0x7FFFu + ((u >> 16) & 1u);
  return (unsigned short)(u >> 16);
}
DEV float bf2f(unsigned short h) { return __uint_as_float(((unsigned int)h) << 16); }

DEV void gload_lds16(const void* g, void* l) {
  __builtin_amdgcn_global_load_lds(
      (const __attribute__((address_space(1))) void*)g,
      (__attribute__((address_space(3))) void*)l, 16, 0, 0);
}

// ---------------- cast kernels ----------------
__global__ void convert_x_kernel(const float* __restrict__ x, unsigned short* __restrict__ xb) {
  int64_t i = ((int64_t)blockIdx.x * 256 + threadIdx.x) * 8;
  float4v a = *(const float4v*)(x + i);
  float4v b = *(const float4v*)(x + i + 4);
  us8 o;
  o[0] = f2bf(a[0]); o[1] = f2bf(a[1]); o[2] = f2bf(a[2]); o[3] = f2bf(a[3]);
  o[4] = f2bf(b[0]); o[5] = f2bf(b[1]); o[6] = f2bf(b[2]); o[7] = f2bf(b[3]);
  *(us8*)(xb + i) = o;
}

__global__ void convert_w_kernel(const float* __restrict__ wq, const float* __restrict__ wk,
                                 const float* __restrict__ wv, unsigned short* __restrict__ wb) {
  int w = blockIdx.x >> 8;
  int blk = blockIdx.x & 255;
  const float* src = (w == 0) ? wq : ((w == 1) ? wk : wv);
  int i = (blk * 256 + (int)threadIdx.x) * 4;
  float4v a = *(const float4v*)(src + i);
  us4 o;
  o[0] = f2bf(a[0]); o[1] = f2bf(a[1]); o[2] = f2bf(a[2]); o[3] = f2bf(a[3]);
  *(us4*)(wb + (w << 18) + i) = o;
}

// ---------------- fused QKV GEMM ----------------
// grid (128 mtiles, 4 ntiles, 3 which). Skips Q/K tiles fully >= L (never read).
__global__ __launch_bounds__(256) void qkv_gemm_kernel(
    const unsigned short* __restrict__ xb, const unsigned short* __restrict__ wb,
    const float* __restrict__ bq, const float* __restrict__ bk, const float* __restrict__ bv,
    const int* __restrict__ ev,
    unsigned short* __restrict__ Qb, unsigned short* __restrict__ Kb,
    unsigned short* __restrict__ VTb)
{
  const int which = blockIdx.z;
  const int m0 = blockIdx.x << 7;
  const int n0 = blockIdx.y << 7;
  if (which < 2) {   // Q/K rows in fully-masked tiles are never read downstream
    const int L = ev[m0 >> 11];
    if ((m0 & 2047) >= L) return;
  }
  const unsigned short* W = wb + ((int64_t)which << 18);
  const int tid = threadIdx.x;
  const int lane = tid & 63, wid = tid >> 6;
  const int lo = lane & 15, hi = lane >> 4;
  const int wrow = wid >> 1, wcol = wid & 1;

  __shared__ alignas(16) unsigned short lA[128 * 64];
  __shared__ alignas(16) unsigned short lB[128 * 64];

  f32x4 acc[4][4];
  #pragma unroll
  for (int i = 0; i < 4; ++i)
    #pragma unroll
    for (int j = 0; j < 4; ++j) acc[i][j] = (f32x4){0.f, 0.f, 0.f, 0.f};

  for (int k0 = 0; k0 < 512; k0 += 64) {
    if (k0) __syncthreads();
    #pragma unroll
    for (int i = 0; i < 4; ++i) {
      const int m = (i << 8) + tid;
      const int mw = (i << 8) + (wid << 6);
      const int row = m >> 3, c = m & 7;
      const int ca = c ^ (row & 7);
      gload_lds16(xb + ((int64_t)(m0 + row) << 9) + k0 + (ca << 3), lA + (mw << 3));
      gload_lds16(W  + ((int64_t)(n0 + row) << 9) + k0 + (ca << 3), lB + (mw << 3));
    }
    __syncthreads();

    #pragma unroll
    for (int ks = 0; ks < 2; ++ks) {
      bf16x8 af[4], bfr[4];
      #pragma unroll
      for (int mf = 0; mf < 4; ++mf) {
        const int row = (wrow << 6) + (mf << 4) + lo;
        const int cc = ((ks << 2) + hi) ^ (row & 7);
        af[mf] = *(const bf16x8*)(lA + (row << 6) + (cc << 3));
      }
      #pragma unroll
      for (int nf = 0; nf < 4; ++nf) {
        const int row = (wcol << 6) + (nf << 4) + lo;
        const int cc = ((ks << 2) + hi) ^ (row & 7);
        bfr[nf] = *(const bf16x8*)(lB + (row << 6) + (cc << 3));
      }
      #pragma unroll
      for (int mf = 0; mf < 4; ++mf)
        #pragma unroll
        for (int nf = 0; nf < 4; ++nf)
          acc[mf][nf] = __builtin_amdgcn_mfma_f32_16x16x32_bf16(af[mf], bfr[nf], acc[mf][nf], 0, 0, 0);
    }
  }

  const float* bias = (which == 0) ? bq : ((which == 1) ? bk : bv);
  if (which < 2) {
    unsigned short* outp = (which == 0) ? Qb : Kb;
    #pragma unroll
    for (int nf = 0; nf < 4; ++nf) {
      const int e = n0 + (wcol << 6) + (nf << 4) + lo;
      const float bb = bias[e];
      #pragma unroll
      for (int mf = 0; mf < 4; ++mf) {
        const int rowg = m0 + (wrow << 6) + (mf << 4) + (hi << 2);
        #pragma unroll
        for (int r = 0; r < 4; ++r)
          outp[((int64_t)(rowg + r) << 9) + e] = f2bf(acc[mf][nf][r] + bb);
      }
    }
  } else {
    #pragma unroll
    for (int nf = 0; nf < 4; ++nf) {
      const int e = n0 + (wcol << 6) + (nf << 4) + lo;
      const float bb = bias[e];
      #pragma unroll
      for (int mf = 0; mf < 4; ++mf) {
        const int rowg = m0 + (wrow << 6) + (mf << 4) + (hi << 2);
        const int bidx = rowg >> 11;
        const int s = rowg & 2047;
        us4 pk;
        pk[0] = f2bf(acc[mf][nf][0] + bb);
        pk[1] = f2bf(acc[mf][nf][1] + bb);
        pk[2] = f2bf(acc[mf][nf][2] + bb);
        pk[3] = f2bf(acc[mf][nf][3] + bb);
        *(us4*)(VTb + (((int64_t)(bidx << 9) + e) << 11) + s) = pk;
      }
    }
  }
}

// ---------------- per-batch mean of V rows ----------------
__global__ void vmean_kernel(const unsigned short* __restrict__ VTb, float* __restrict__ vmean) {
  const int row = blockIdx.x;  // b*512 + d
  const unsigned short* src = VTb + (int64_t)row * SEQ;
  const int tid = threadIdx.x;
  us8 v = *(const us8*)(src + tid * 8);
  float s = 0.f;
  #pragma unroll
  for (int j = 0; j < 8; ++j) s += bf2f(v[j]);
  #pragma unroll
  for (int off = 1; off < 64; off <<= 1) s += __shfl_xor(s, off);
  __shared__ float ps[4];
  const int lane = tid & 63, wid = tid >> 6;
  if (lane == 0) ps[wid] = s;
  __syncthreads();
  if (tid == 0) vmean[row] = (ps[0] + ps[1] + ps[2] + ps[3]) * (1.f / 2048.f);
}

// ---------------- pass 1: P = exp(Q K^T * inv_scale), masked, bf16 ----------------
// grid (16 qtiles, 16 ktiles, nb batches), 256 thr. P[z][2048][2048].
__global__ __launch_bounds__(256) void score_gemm_kernel(
    const unsigned short* __restrict__ Qb, const unsigned short* __restrict__ Kb,
    const int* __restrict__ ev, unsigned short* __restrict__ P, int b0)
{
  const int z = blockIdx.z;
  const int b = b0 + z;
  const int L = ev[b];
  const int q0 = blockIdx.x << 7;
  const int k0g = blockIdx.y << 7;
  if (q0 >= L || k0g >= L) return;   // tile never read by pv pass

  const unsigned short* Qrows = Qb + ((int64_t)b << 20);
  const unsigned short* Krows = Kb + ((int64_t)b << 20);
  const int tid = threadIdx.x;
  const int lane = tid & 63, wid = tid >> 6;
  const int lo = lane & 15, hi = lane >> 4;
  const int wrow = wid >> 1, wcol = wid & 1;

  __shared__ alignas(16) unsigned short lA[128 * 64];
  __shared__ alignas(16) unsigned short lB[128 * 64];

  f32x4 acc[4][4];
  #pragma unroll
  for (int i = 0; i < 4; ++i)
    #pragma unroll
    for (int j = 0; j < 4; ++j) acc[i][j] = (f32x4){0.f, 0.f, 0.f, 0.f};

  for (int k0 = 0; k0 < 512; k0 += 64) {   // contraction over d
    if (k0) __syncthreads();
    #pragma unroll
    for (int i = 0; i < 4; ++i) {
      const int m = (i << 8) + tid;
      const int mw = (i << 8) + (wid << 6);
      const int row = m >> 3, c = m & 7;
      const int ca = c ^ (row & 7);
      gload_lds16(Qrows + ((int64_t)(q0 + row) << 9) + k0 + (ca << 3), lA + (mw << 3));
      gload_lds16(Krows + ((int64_t)(k0g + row) << 9) + k0 + (ca << 3), lB + (mw << 3));
    }
    __syncthreads();

    #pragma unroll
    for (int ks = 0; ks < 2; ++ks) {
      bf16x8 af[4], bfr[4];
      #pragma unroll
      for (int mf = 0; mf < 4; ++mf) {
        const int row = (wrow << 6) + (mf << 4) + lo;
        const int cc = ((ks << 2) + hi) ^ (row & 7);
        af[mf] = *(const bf16x8*)(lA + (row << 6) + (cc << 3));
      }
      #pragma unroll
      for (int nf = 0; nf < 4; ++nf) {
        const int row = (wcol << 6) + (nf << 4) + lo;
        const int cc = ((ks << 2) + hi) ^ (row & 7);
        bfr[nf] = *(const bf16x8*)(lB + (row << 6) + (cc << 3));
      }
      #pragma unroll
      for (int mf = 0; mf < 4; ++mf)
        #pragma unroll
        for (int nf = 0; nf < 4; ++nf)
          acc[mf][nf] = __builtin_amdgcn_mfma_f32_16x16x32_bf16(af[mf], bfr[nf], acc[mf][nf], 0, 0, 0);
    }
  }

  // epilogue: p = exp2(s*SEXP) with mask, bf16 store
  unsigned short* Pz = P + ((int64_t)z << 22);
  #pragma unroll
  for (int nf = 0; nf < 4; ++nf) {
    const int kcol = k0g + (wcol << 6) + (nf << 4) + lo;
    const bool kok = kcol < L;
    #pragma unroll
    for (int mf = 0; mf < 4; ++mf) {
      const int rowg = q0 + (wrow << 6) + (mf << 4) + (hi << 2);
      #pragma unroll
      for (int r = 0; r < 4; ++r) {
        const float p = (kok && (rowg + r < L)) ? exp2f(acc[mf][nf][r] * SEXP) : 0.f;
        Pz[((int64_t)(rowg + r) << 11) + kcol] = f2bf(p);
      }
    }
  }
}

// ---------------- pass 2: O = P V / rowsum(P), rows>=L -> vmean ----------------
// grid (16 qtiles of 128, 4 dtiles, nb batches), 512 thr = 8 waves (4q x 2d).
// v4: r12 dbuf skeleton, fatter block (128q x 128d) halves V re-staging volume.
__global__ __launch_bounds__(512) void pv_gemm_kernel(
    const unsigned short* __restrict__ P, const unsigned short* __restrict__ VTb,
    const float* __restrict__ vmean, const int* __restrict__ ev,
    float* __restrict__ out, int b0)
{
  const int z = blockIdx.z;
  const int b = b0 + z;
  const int L = ev[b];
  const int q0 = blockIdx.x << 7;   // 128 q-rows
  const int d0 = blockIdx.y << 7;   // 128 d-cols
  const int tid = threadIdx.x;

  float* outb = out + ((int64_t)b << 20);
  const float* vm = vmean + (b << 9);

  if (q0 >= L) {  // fully masked q-tile: uniform average of all V rows
    #pragma unroll
    for (int j = 0; j < 8; ++j) {
      const int idx = tid + (j << 9);          // 0..4095 float4s = 128x128 f32
      const int r = idx >> 5, c = (idx & 31) << 2;
      *(float4v*)(outb + ((int64_t)(q0 + r) << 9) + d0 + c) = *(const float4v*)(vm + d0 + c);
    }
    return;
  }

  const int lane = tid & 63, wid = tid >> 6;
  const int lo = lane & 15, hi = lane >> 4;
  const int qsub = wid & 3, dsub = wid >> 2;   // wave tile: 32q x 64d

  __shared__ alignas(16) unsigned short lA[2][128 * 64];   // P tile dbuf (32 KB)
  __shared__ alignas(16) unsigned short lB[2][128 * 64];   // V^T tile dbuf (32 KB)
  __shared__ float lpart[128][4];

  const unsigned short* Pz = P + ((int64_t)z << 22);
  const unsigned short* Vrows = VTb + ((int64_t)(b << 9) << 11);

  f32x4 acc[2][4];
  #pragma unroll
  for (int i = 0; i < 2; ++i)
    #pragma unroll
    for (int j = 0; j < 4; ++j) acc[i][j] = (f32x4){0.f, 0.f, 0.f, 0.f};
  float ls[2] = {0.f, 0.f};

  const int nk = (L + 63) >> 6;

  auto stage = [&](int cur, int kk) {
    #pragma unroll
    for (int i = 0; i < 2; ++i) {            // A = P[128][64]: 1024 chunks / 512 thr
      const int m = (i << 9) + tid;
      const int mw = (i << 9) + (wid << 6);
      const int row = m >> 3, c = m & 7;
      const int ca = c ^ (row & 7);
      gload_lds16(Pz + ((int64_t)(q0 + row) << 11) + (kk << 6) + (ca << 3),
                  &lA[cur][mw << 3]);
    }
    #pragma unroll
    for (int i = 0; i < 2; ++i) {            // B = VT[128][64]
      const int m = (i << 9) + tid;
      const int mw = (i << 9) + (wid << 6);
      const int row = m >> 3, c = m & 7;
      const int ca = c ^ (row & 7);
      gload_lds16(Vrows + ((int64_t)(d0 + row) << 11) + (kk << 6) + (ca << 3),
                  &lB[cur][mw << 3]);
    }
  };

  stage(0, 0);
  __syncthreads();
  int cur = 0;

  for (int kk = 0; kk < nk; ++kk) {
    if (kk + 1 < nk) stage(cur ^ 1, kk + 1);   // prefetch next round

    #pragma unroll
    for (int ks = 0; ks < 2; ++ks) {
      bf16x8 af[2], bfr[4];
      #pragma unroll
      for (int mf = 0; mf < 2; ++mf) {
        const int row = (qsub << 5) + (mf << 4) + lo;
        const int cc = ((ks << 2) + hi) ^ (row & 7);
        af[mf] = *(const bf16x8*)(&lA[cur][(row << 6) + (cc << 3)]);
      }
      #pragma unroll
      for (int nf = 0; nf < 4; ++nf) {
        const int row = (dsub << 6) + (nf << 4) + lo;
        const int cc = ((ks << 2) + hi) ^ (row & 7);
        bfr[nf] = *(const bf16x8*)(&lB[cur][(row << 6) + (cc << 3)]);
      }
      if (dsub == 0) {  // row-sums of P from A fragments (l accumulation)
        #pragma unroll
        for (int mf = 0; mf < 2; ++mf) {
          float t = 0.f;
          #pragma unroll
          for (int j = 0; j < 8; ++j) t += bf2f((unsigned short)af[mf][j]);
          ls[mf] += t;
        }
      }
      #pragma unroll
      for (int mf = 0; mf < 2; ++mf)
        #pragma unroll
        for (int nf = 0; nf < 4; ++nf)
          acc[mf][nf] = __builtin_amdgcn_mfma_f32_16x16x32_bf16(af[mf], bfr[nf], acc[mf][nf], 0, 0, 0);
    }

    __syncthreads();
    cur ^= 1;
  }

  if (dsub == 0) {
    #pragma unroll
    for (int mf = 0; mf < 2; ++mf)
      lpart[(qsub << 5) + (mf << 4) + lo][hi] = ls[mf];
  }
  __syncthreads();

  // epilogue: normalize, mask tail rows to vmean
  #pragma unroll
  for (int mf = 0; mf < 2; ++mf) {
    const int rowb = (qsub << 5) + (mf << 4) + (hi << 2);
    float rl[4];
    #pragma unroll
    for (int r = 0; r < 4; ++r) {
      const float l = lpart[rowb + r][0] + lpart[rowb + r][1] +
                      lpart[rowb + r][2] + lpart[rowb + r][3];
      rl[r] = 1.0f / l;
    }
    #pragma unroll
    for (int nf = 0; nf < 4; ++nf) {
      const int col = d0 + (dsub << 6) + (nf << 4) + lo;
      const float vmc = vm[col];
      #pragma unroll
      for (int r = 0; r < 4; ++r) {
        const int rowg = q0 + rowb + r;
        const float val = (rowg < L) ? (acc[mf][nf][r] * rl[r]) : vmc;
        outb[((int64_t)rowg << 9) + col] = val;
      }
    }
  }
}

// ---------------- launcher ----------------
extern "C" void kernel_launch(void* const* d_in, const int* in_sizes, int n_in,
                              void* d_out, int out_size, void* d_ws, size_t ws_size,
                              hipStream_t stream) {
  const float* x  = (const float*)d_in[0];
  const int* ev   = (const int*)d_in[1];
  const float* Wq = (const float*)d_in[2];
  const float* bq = (const float*)d_in[3];
  const float* Wk = (const float*)d_in[4];
  const float* bk = (const float*)d_in[5];
  const float* Wv = (const float*)d_in[6];
  const float* bv = (const float*)d_in[7];
  float* out = (float*)d_out;

  unsigned short* xb  = (unsigned short*)d_ws;          // [16384][512]; dead after qkv
  unsigned short* wb  = xb + (int64_t)16384 * 512;      // [3][512][512]
  unsigned short* Qb  = wb + 3 * 512 * 512;             // [16384][512]
  unsigned short* Kb  = Qb + (int64_t)16384 * 512;      // [16384][512]
  unsigned short* VTb = Kb + (int64_t)16384 * 512;      // [8][512][2048]
  float* vmean = (float*)(VTb + (int64_t)16384 * 512);  // [8][512]
  unsigned short* Ptail = (unsigned short*)(vmean + 8 * 512);

  // pick largest per-pass batch count that fits the workspace
  const size_t base_bytes = (size_t)((char*)Ptail - (char*)d_ws);  // 85,475,328
  const size_t pbytes = (size_t)SEQ * SEQ * 2;                     // 8 MB per batch
  int nb;
  unsigned short* P;
  if (ws_size >= base_bytes + 8 * pbytes)      { nb = 8; P = Ptail; }
  else if (ws_size >= base_bytes + 4 * pbytes) { nb = 4; P = Ptail; }
  else                                         { nb = 2; P = xb; }  // alias fallback

  convert_x_kernel<<<4096, 256, 0, stream>>>(x, xb);
  convert_w_kernel<<<768, 256, 0, stream>>>(Wq, Wk, Wv, wb);
  qkv_gemm_kernel<<<dim3(128, 4, 3), 256, 0, stream>>>(xb, wb, bq, bk, bv, ev, Qb, Kb, VTb);
  vmean_kernel<<<4096, 256, 0, stream>>>(VTb, vmean);

  for (int c = 0; c < 8 / nb; ++c) {
    score_gemm_kernel<<<dim3(16, 16, nb), 256, 0, stream>>>(Qb, Kb, ev, P, c * nb);
    pv_gemm_kernel<<<dim3(16, 4, nb), 512, 0, stream>>>(P, VTb, vmean, ev, out, c * nb);
  }
}